// Round 1
// baseline (3146.155 us; speedup 1.0000x reference)
//
#include <hip/hip_runtime.h>
#include <cstdint>
#include <cmath>

#define T_SEQ 1024
#define BATCH 16
#define HID 96
#define G4 384
#define QKV_LD 288
#define HDIM 24
#define KKEEP 512
#define SCALE 0.20412414523193154f  // 1/sqrt(24)

__device__ __forceinline__ float wred_sum(float v){
#pragma unroll
  for (int o=32;o;o>>=1) v += __shfl_xor(v,o,64);
  return v;
}
__device__ __forceinline__ float wred_max(float v){
#pragma unroll
  for (int o=32;o;o>>=1) v = fmaxf(v,__shfl_xor(v,o,64));
  return v;
}
__device__ __forceinline__ int wred_sumi(int v){
#pragma unroll
  for (int o=32;o;o>>=1) v += __shfl_xor(v,o,64);
  return v;
}
__device__ __forceinline__ unsigned fmono(float f){
  unsigned u = __float_as_uint(f);
  return (u & 0x80000000u) ? ~u : (u | 0x80000000u);
}

// ---------------- generic tiled GEMM: C[m, coff+n] = act(A[M,K] @ W[N,K]^T + b1 + b2)
__global__ __launch_bounds__(256)
void gemm_kernel(const float* __restrict__ A, const float* __restrict__ W,
                 const float* __restrict__ b1, const float* __restrict__ b2,
                 float* __restrict__ C, int M, int N, int K,
                 int ldc, int coff, int relu)
{
  __shared__ float As[16][68];
  __shared__ float Ws[16][68];
  const int tid = threadIdx.x;
  const int tx = tid & 15, ty = tid >> 4;
  const int m0 = blockIdx.y * 64, n0 = blockIdx.x * 64;
  const int lrow = tid >> 2, lcol = (tid & 3) * 4;
  float acc[4][4] = {};
  for (int k0 = 0; k0 < K; k0 += 16) {
    float4 a = {0,0,0,0}, w = {0,0,0,0};
    int gm = m0 + lrow;
    if (gm < M) a = *(const float4*)(A + (size_t)gm*K + k0 + lcol);
    int gn = n0 + lrow;
    if (gn < N) w = *(const float4*)(W + (size_t)gn*K + k0 + lcol);
    __syncthreads();
    As[lcol+0][lrow]=a.x; As[lcol+1][lrow]=a.y; As[lcol+2][lrow]=a.z; As[lcol+3][lrow]=a.w;
    Ws[lcol+0][lrow]=w.x; Ws[lcol+1][lrow]=w.y; Ws[lcol+2][lrow]=w.z; Ws[lcol+3][lrow]=w.w;
    __syncthreads();
#pragma unroll
    for (int kk=0;kk<16;++kk){
      const float4 av = *(const float4*)&As[kk][ty*4];
      const float4 wv = *(const float4*)&Ws[kk][tx*4];
      float a_[4]={av.x,av.y,av.z,av.w};
      float w_[4]={wv.x,wv.y,wv.z,wv.w};
#pragma unroll
      for (int i=0;i<4;++i)
#pragma unroll
        for (int j=0;j<4;++j) acc[i][j] += a_[i]*w_[j];
    }
  }
#pragma unroll
  for (int i=0;i<4;++i){
    int gm = m0 + ty*4 + i;
    if (gm >= M) continue;
#pragma unroll
    for (int j=0;j<4;++j){
      int gn = n0 + tx*4 + j;
      if (gn >= N) continue;
      float v = acc[i][j];
      if (b1) v += b1[gn];
      if (b2) v += b2[gn];
      if (relu) v = fmaxf(v, 0.f);
      C[(size_t)gm*ldc + coff + gn] = v;
    }
  }
}

// ---------------- sequential LSTM (input-side GEMM precomputed into `pre`)
// grid: BATCH blocks; block: 768 threads (2 threads per gate)
__global__ __launch_bounds__(768)
void lstm_kernel(const float* __restrict__ pre, const float* __restrict__ w_hh,
                 float* __restrict__ hout)
{
  const int b = blockIdx.x;
  const int tid = threadIdx.x;
  const int g = tid >> 1, half = tid & 1;
  float w[48];
  {
    const float* wp = w_hh + g*96 + half*48;
#pragma unroll
    for (int j=0;j<48;j+=4){
      float4 t = *(const float4*)(wp + j);
      w[j]=t.x; w[j+1]=t.y; w[j+2]=t.z; w[j+3]=t.w;
    }
  }
  __shared__ float h_lds[96];
  __shared__ float gate_lds[384];
  float c = 0.f;
  if (tid < 96) h_lds[tid] = 0.f;
  __syncthreads();
  const float* prow = pre + (size_t)b*T_SEQ*G4;
  float* hrow = hout + (size_t)b*T_SEQ*HID;
  for (int t=0; t<T_SEQ; ++t){
    const float* hb = h_lds + half*48;
    float a0=0.f,a1=0.f,a2=0.f,a3=0.f;
#pragma unroll
    for (int j=0;j<48;j+=4){
      a0 += w[j]*hb[j]; a1 += w[j+1]*hb[j+1];
      a2 += w[j+2]*hb[j+2]; a3 += w[j+3]*hb[j+3];
    }
    float acc = (a0+a1)+(a2+a3);
    acc += __shfl_xor(acc, 1, 64);
    if (half == 0) gate_lds[g] = acc + prow[g];
    __syncthreads();
    if (tid < 96){
      float ig = gate_lds[tid], fg = gate_lds[96+tid];
      float gg = gate_lds[192+tid], og = gate_lds[288+tid];
      float is = 1.f/(1.f+expf(-ig));
      float fs = 1.f/(1.f+expf(-fg));
      float gt = tanhf(gg);
      float os = 1.f/(1.f+expf(-og));
      c = fs*c + is*gt;
      float hv = os * tanhf(c);
      h_lds[tid] = hv;
      hrow[tid] = hv;
    }
    __syncthreads();
    prow += G4; hrow += HID;
  }
}

// ---------------- attention over full rows (sparse top-k optional)
// qkv layout: [B*T][288] (q|k|v). One wave per q-row, 8 rows/WG share staged K/V.
__global__ __launch_bounds__(512)
void attn_kernel(const float* __restrict__ qkv, float* __restrict__ out, int sparse)
{
  __shared__ float kl[24][260];
  const int tid = threadIdx.x;
  const int wave = tid >> 6, lane = tid & 63;
  const int bh = blockIdx.x >> 7;            // 128 blocks per (b,h)
  const int b = bh >> 2, h = bh & 3;
  const int tq = ((blockIdx.x & 127) << 3) + wave;
  const size_t base = (size_t)b * T_SEQ;
  const int hoff = h * HDIM;
  float q[24];
  {
    const float* qp = qkv + (base + tq)*QKV_LD + hoff;
#pragma unroll
    for (int d4=0; d4<6; ++d4){
      float4 t = *(const float4*)(qp + d4*4);
      q[d4*4]=t.x; q[d4*4+1]=t.y; q[d4*4+2]=t.z; q[d4*4+3]=t.w;
    }
  }
  float sc[16];
  // pass A: scores (lane owns s = c*256 + lane*4 + j)
  for (int c=0;c<4;++c){
    __syncthreads();
#pragma unroll
    for (int rep=0;rep<3;++rep){
      int p = rep*512 + tid;
      int sl = p/6, d4 = p - sl*6;
      const float4 kv = *(const float4*)(qkv + (base + (c<<8) + sl)*QKV_LD + 96 + hoff + d4*4);
      kl[d4*4+0][sl]=kv.x; kl[d4*4+1][sl]=kv.y; kl[d4*4+2][sl]=kv.z; kl[d4*4+3][sl]=kv.w;
    }
    __syncthreads();
    float a0=0.f,a1=0.f,a2=0.f,a3=0.f;
#pragma unroll
    for (int d=0; d<24; ++d){
      const float4 kd = *(const float4*)&kl[d][lane*4];
      a0 += q[d]*kd.x; a1 += q[d]*kd.y; a2 += q[d]*kd.z; a3 += q[d]*kd.w;
    }
    sc[c*4+0]=a0*SCALE; sc[c*4+1]=a1*SCALE; sc[c*4+2]=a2*SCALE; sc[c*4+3]=a3*SCALE;
  }
  // softmax (+ exact top-k mask)
  float m_loc = sc[0];
#pragma unroll
  for (int i=1;i<16;++i) m_loc = fmaxf(m_loc, sc[i]);
  const float m = wred_max(m_loc);
  float sum_loc = 0.f;
  if (sparse){
    unsigned u[16];
#pragma unroll
    for (int i=0;i<16;++i) u[i] = fmono(sc[i]);
    unsigned prefix = 0;
    for (int bit=31; bit>=0; --bit){
      unsigned test = prefix | (1u<<bit);
      int cnt = 0;
#pragma unroll
      for (int i=0;i<16;++i) cnt += (u[i] >= test) ? 1 : 0;
      cnt = wred_sumi(cnt);
      if (cnt >= KKEEP) prefix = test;
    }
#pragma unroll
    for (int i=0;i<16;++i){
      float e = (u[i] >= prefix) ? __expf(sc[i]-m) : 0.f;
      sc[i] = e; sum_loc += e;
    }
  } else {
#pragma unroll
    for (int i=0;i<16;++i){
      float e = __expf(sc[i]-m);
      sc[i] = e; sum_loc += e;
    }
  }
  const float inv = 1.f / wred_sum(sum_loc);
#pragma unroll
  for (int i=0;i<16;++i) sc[i] *= inv;
  // pass B: PV
  float acc[24] = {};
  for (int c=0;c<4;++c){
    __syncthreads();
#pragma unroll
    for (int rep=0;rep<3;++rep){
      int p = rep*512 + tid;
      int sl = p/6, d4 = p - sl*6;
      const float4 vv = *(const float4*)(qkv + (base + (c<<8) + sl)*QKV_LD + 192 + hoff + d4*4);
      kl[d4*4+0][sl]=vv.x; kl[d4*4+1][sl]=vv.y; kl[d4*4+2][sl]=vv.z; kl[d4*4+3][sl]=vv.w;
    }
    __syncthreads();
    const float w0=sc[c*4], w1=sc[c*4+1], w2=sc[c*4+2], w3=sc[c*4+3];
#pragma unroll
    for (int d=0; d<24; ++d){
      const float4 vd = *(const float4*)&kl[d][lane*4];
      acc[d] += w0*vd.x + w1*vd.y + w2*vd.z + w3*vd.w;
    }
  }
#pragma unroll
  for (int d=0; d<24; ++d) acc[d] = wred_sum(acc[d]);
  if (lane == 0){
    float* op = out + (base + tq)*HID + hoff;
#pragma unroll
    for (int d4=0; d4<6; ++d4){
      float4 t = {acc[d4*4], acc[d4*4+1], acc[d4*4+2], acc[d4*4+3]};
      *(float4*)(op + d4*4) = t;
    }
  }
}

// ---------------- dense attention for t = T-1 only (encoder 2): 64 rows, 1 wave each
__global__ __launch_bounds__(64)
void attn_last_kernel(const float* __restrict__ qkv, float* __restrict__ out)
{
  const int bh = blockIdx.x, b = bh>>2, h = bh&3;
  const int lane = threadIdx.x;
  const size_t base = (size_t)b*T_SEQ;
  const int hoff = h*HDIM;
  float q[24];
  {
    const float* qp = qkv + (base + T_SEQ-1)*QKV_LD + hoff;
#pragma unroll
    for (int d4=0; d4<6; ++d4){
      float4 t = *(const float4*)(qp + d4*4);
      q[d4*4]=t.x; q[d4*4+1]=t.y; q[d4*4+2]=t.z; q[d4*4+3]=t.w;
    }
  }
  float sc[16];
#pragma unroll 4
  for (int i=0;i<16;++i){
    const float* kp = qkv + (base + i*64 + lane)*QKV_LD + 96 + hoff;
    float a = 0.f;
#pragma unroll
    for (int d4=0; d4<6; ++d4){
      float4 kv = *(const float4*)(kp + d4*4);
      a += q[d4*4]*kv.x + q[d4*4+1]*kv.y + q[d4*4+2]*kv.z + q[d4*4+3]*kv.w;
    }
    sc[i] = a*SCALE;
  }
  float m_loc = sc[0];
#pragma unroll
  for (int i=1;i<16;++i) m_loc = fmaxf(m_loc, sc[i]);
  const float m = wred_max(m_loc);
  float sum_loc = 0.f;
#pragma unroll
  for (int i=0;i<16;++i){ sc[i] = __expf(sc[i]-m); sum_loc += sc[i]; }
  const float inv = 1.f / wred_sum(sum_loc);
  float acc[24] = {};
#pragma unroll 4
  for (int i=0;i<16;++i){
    const float* vp = qkv + (base + i*64 + lane)*QKV_LD + 192 + hoff;
    const float wgt = sc[i]*inv;
#pragma unroll
    for (int d4=0; d4<6; ++d4){
      float4 vv = *(const float4*)(vp + d4*4);
      acc[d4*4]   += wgt*vv.x; acc[d4*4+1] += wgt*vv.y;
      acc[d4*4+2] += wgt*vv.z; acc[d4*4+3] += wgt*vv.w;
    }
  }
#pragma unroll
  for (int d=0; d<24; ++d) acc[d] = wred_sum(acc[d]);
  if (lane == 0){
    float* op = out + (base + T_SEQ-1)*HID + hoff;
#pragma unroll
    for (int d4=0; d4<6; ++d4){
      float4 t = {acc[d4*4], acc[d4*4+1], acc[d4*4+2], acc[d4*4+3]};
      *(float4*)(op + d4*4) = t;
    }
  }
}

// ---------------- out = LayerNorm(x + y) * w + b ; one wave per 96-wide row
__global__ __launch_bounds__(256)
void resln_kernel(const float* __restrict__ x, const float* __restrict__ y,
                  const float* __restrict__ w, const float* __restrict__ bb,
                  float* __restrict__ out)
{
  const int row = blockIdx.x*4 + (threadIdx.x>>6);
  const int lane = threadIdx.x & 63;
  const float* xr = x + (size_t)row*HID;
  const float* yr = y + (size_t)row*HID;
  float v0 = xr[lane] + yr[lane];
  float v1 = (lane < 32) ? (xr[64+lane] + yr[64+lane]) : 0.f;
  float mu = wred_sum(v0+v1) * (1.f/96.f);
  float d0 = v0-mu, d1 = (lane<32) ? (v1-mu) : 0.f;
  float var = wred_sum(d0*d0 + d1*d1) * (1.f/96.f);
  float rs = rsqrtf(var + 1e-5f);
  float* orow = out + (size_t)row*HID;
  orow[lane] = d0*rs*w[lane] + bb[lane];
  if (lane < 32) orow[64+lane] = d1*rs*w[64+lane] + bb[64+lane];
}

// ---------------- encoder-2 tail at t=T-1 only: proj+LN1+FF+LN2+fc
__device__ __forceinline__ float block_sum_192(float v, float* red){
  v = wred_sum(v);
  const int tid = threadIdx.x;
  if ((tid & 63) == 0) red[tid>>6] = v;
  __syncthreads();
  float r = red[0]+red[1]+red[2];
  __syncthreads();
  return r;
}

__global__ __launch_bounds__(192)
void tail_kernel(const float* __restrict__ xin, const float* __restrict__ mha,
                 const float* __restrict__ out_w, const float* __restrict__ out_b,
                 const float* __restrict__ l1_w, const float* __restrict__ l1_b,
                 const float* __restrict__ l2_w, const float* __restrict__ l2_b,
                 const float* __restrict__ ln1w, const float* __restrict__ ln1b,
                 const float* __restrict__ ln2w, const float* __restrict__ ln2b,
                 const float* __restrict__ fcw, const float* __restrict__ fcb,
                 float* __restrict__ outp)
{
  const int b = blockIdx.x, tid = threadIdx.x;
  __shared__ float y[96], f1[192], mrow[96], red[3];
  const size_t row = ((size_t)b*T_SEQ + T_SEQ-1)*HID;
  if (tid < 96) mrow[tid] = mha[row + tid];
  __syncthreads();
  float r = 0.f;
  if (tid < 96){
    float p = out_b[tid];
    const float* wr = out_w + tid*96;
#pragma unroll 4
    for (int d=0; d<96; ++d) p += mrow[d]*wr[d];
    r = xin[row + tid] + p;
  }
  float mu = block_sum_192(tid<96 ? r : 0.f, red) * (1.f/96.f);
  float dv = tid<96 ? r-mu : 0.f;
  float var = block_sum_192(dv*dv, red) * (1.f/96.f);
  float rs = rsqrtf(var + 1e-5f);
  if (tid < 96) y[tid] = dv*rs*ln1w[tid] + ln1b[tid];
  __syncthreads();
  {
    float a = l1_b[tid];
    const float* wr = l1_w + tid*96;
#pragma unroll 4
    for (int d=0; d<96; ++d) a += y[d]*wr[d];
    f1[tid] = fmaxf(a, 0.f);
  }
  __syncthreads();
  float r2 = 0.f;
  if (tid < 96){
    float a = l2_b[tid];
    const float* wr = l2_w + tid*192;
#pragma unroll 4
    for (int d=0; d<192; ++d) a += f1[d]*wr[d];
    r2 = y[tid] + a;
  }
  float mu2 = block_sum_192(tid<96 ? r2 : 0.f, red) * (1.f/96.f);
  float dv2 = tid<96 ? r2-mu2 : 0.f;
  float var2 = block_sum_192(dv2*dv2, red) * (1.f/96.f);
  float rs2 = rsqrtf(var2 + 1e-5f);
  float z = tid<96 ? (dv2*rs2*ln2w[tid] + ln2b[tid]) : 0.f;
  float tot = block_sum_192(tid<96 ? z*fcw[tid] : 0.f, red);
  if (tid == 0) outp[b] = tot + fcb[0];
}

extern "C" void kernel_launch(void* const* d_in, const int* in_sizes, int n_in,
                              void* d_out, int out_size, void* d_ws, size_t ws_size,
                              hipStream_t stream)
{
  const float* x     = (const float*)d_in[0];
  const float* w_ih0 = (const float*)d_in[1];
  const float* w_hh0 = (const float*)d_in[2];
  const float* b_ih0 = (const float*)d_in[3];
  const float* b_hh0 = (const float*)d_in[4];
  const float* w_ih1 = (const float*)d_in[5];
  const float* w_hh1 = (const float*)d_in[6];
  const float* b_ih1 = (const float*)d_in[7];
  const float* b_hh1 = (const float*)d_in[8];
  const float* qw = (const float*)d_in[9];
  const float* kw = (const float*)d_in[10];
  const float* vw = (const float*)d_in[11];
  const float* ow = (const float*)d_in[12];
  const float* enc_in_w  = (const float*)d_in[13];
  const float* enc_in_b  = (const float*)d_in[14];
  const float* enc_out_w = (const float*)d_in[15];
  const float* enc_out_b = (const float*)d_in[16];
  const float* enc_l1_w  = (const float*)d_in[17];
  const float* enc_l1_b  = (const float*)d_in[18];
  const float* enc_l2_w  = (const float*)d_in[19];
  const float* enc_l2_b  = (const float*)d_in[20];
  const float* enc_ln1_w = (const float*)d_in[21];
  const float* enc_ln1_b = (const float*)d_in[22];
  const float* enc_ln2_w = (const float*)d_in[23];
  const float* enc_ln2_b = (const float*)d_in[24];
  const float* fc_w = (const float*)d_in[25];
  const float* fc_b = (const float*)d_in[26];
  float* outp = (float*)d_out;

  float* ws = (float*)d_ws;
  const size_t MT = (size_t)BATCH*T_SEQ;   // 16384
  float* pre  = ws;                        // 16384*384 (also qkv[288] / ff1[192])
  float* bufA = pre  + MT*G4;
  float* bufB = bufA + MT*HID;
  float* bufC = bufB + MT*HID;

  const int M = (int)MT;
  auto gemm = [&](const float* A, const float* W, const float* bb1, const float* bb2,
                  float* C, int N, int K, int ldc, int coff, int relu){
    dim3 grid((N+63)/64, M/64);
    gemm_kernel<<<grid, dim3(256), 0, stream>>>(A, W, bb1, bb2, C, M, N, K, ldc, coff, relu);
  };

  // LSTM layer 0
  gemm(x, w_ih0, b_ih0, b_hh0, pre, 384, 64, 384, 0, 0);
  lstm_kernel<<<dim3(BATCH), dim3(768), 0, stream>>>(pre, w_hh0, bufA);
  // LSTM layer 1
  gemm(bufA, w_ih1, b_ih1, b_hh1, pre, 384, 96, 384, 0, 0);
  lstm_kernel<<<dim3(BATCH), dim3(768), 0, stream>>>(pre, w_hh1, bufB);
  // sparse attention
  gemm(bufB, qw, nullptr, nullptr, pre, 96, 96, QKV_LD, 0,   0);
  gemm(bufB, kw, nullptr, nullptr, pre, 96, 96, QKV_LD, 96,  0);
  gemm(bufB, vw, nullptr, nullptr, pre, 96, 96, QKV_LD, 192, 0);
  attn_kernel<<<dim3(8192), dim3(512), 0, stream>>>(pre, bufA, 1);
  gemm(bufA, ow, nullptr, nullptr, bufB, 96, 96, 96, 0, 0);
  // encoder layer 0 (full)
  gemm(bufB, enc_in_w, enc_in_b, nullptr, pre, 288, 96, QKV_LD, 0, 0);
  attn_kernel<<<dim3(8192), dim3(512), 0, stream>>>(pre, bufA, 0);
  gemm(bufA, enc_out_w, enc_out_b, nullptr, bufC, 96, 96, 96, 0, 0);
  resln_kernel<<<dim3(4096), dim3(256), 0, stream>>>(bufB, bufC, enc_ln1_w, enc_ln1_b, bufB);
  gemm(bufB, enc_l1_w, enc_l1_b, nullptr, pre, 192, 96, 192, 0, 1);
  gemm(pre, enc_l2_w, enc_l2_b, nullptr, bufC, 96, 192, 96, 0, 0);
  resln_kernel<<<dim3(4096), dim3(256), 0, stream>>>(bufB, bufC, enc_ln2_w, enc_ln2_b, bufB);
  // encoder layer 1 — only t = T-1 reaches the output head
  gemm(bufB, enc_in_w + 288*96, enc_in_b + 288, nullptr, pre, 288, 96, QKV_LD, 0, 0);
  attn_last_kernel<<<dim3(64), dim3(64), 0, stream>>>(pre, bufA);
  tail_kernel<<<dim3(BATCH), dim3(192), 0, stream>>>(
      bufB, bufA,
      enc_out_w + 96*96, enc_out_b + 96,
      enc_l1_w + 192*96, enc_l1_b + 192,
      enc_l2_w + 96*192, enc_l2_b + 96,
      enc_ln1_w + 96, enc_ln1_b + 96,
      enc_ln2_w + 96, enc_ln2_b + 96,
      fc_w, fc_b, outp);
}

// Round 2
// 2259.230 us; speedup vs baseline: 1.3926x; 1.3926x over previous
//
#include <hip/hip_runtime.h>
#include <cstdint>
#include <cmath>

#define T_SEQ 1024
#define BATCH 16
#define HID 96
#define G4 384
#define QKV_LD 288
#define HDIM 24
#define KKEEP 512
#define SCALE 0.20412414523193154f  // 1/sqrt(24)

__device__ __forceinline__ float wred_sum(float v){
#pragma unroll
  for (int o=32;o;o>>=1) v += __shfl_xor(v,o,64);
  return v;
}
__device__ __forceinline__ float wred_max(float v){
#pragma unroll
  for (int o=32;o;o>>=1) v = fmaxf(v,__shfl_xor(v,o,64));
  return v;
}
__device__ __forceinline__ int wred_sumi(int v){
#pragma unroll
  for (int o=32;o;o>>=1) v += __shfl_xor(v,o,64);
  return v;
}
__device__ __forceinline__ unsigned fmono(float f){
  unsigned u = __float_as_uint(f);
  return (u & 0x80000000u) ? ~u : (u | 0x80000000u);
}
__device__ __forceinline__ float fast_sig(float x){
  return __builtin_amdgcn_rcpf(1.f + __expf(-x));
}
__device__ __forceinline__ float fast_tanh(float x){
  return 1.f - 2.f*__builtin_amdgcn_rcpf(1.f + __expf(2.f*x));
}

// ---------------- generic tiled GEMM: C[m, coff+n] = act(A[M,K] @ W[N,K]^T + b1 + b2)
__global__ __launch_bounds__(256)
void gemm_kernel(const float* __restrict__ A, const float* __restrict__ W,
                 const float* __restrict__ b1, const float* __restrict__ b2,
                 float* __restrict__ C, int M, int N, int K,
                 int ldc, int coff, int relu)
{
  __shared__ float As[16][68];
  __shared__ float Ws[16][68];
  const int tid = threadIdx.x;
  const int tx = tid & 15, ty = tid >> 4;
  const int m0 = blockIdx.y * 64, n0 = blockIdx.x * 64;
  const int lrow = tid >> 2, lcol = (tid & 3) * 4;
  float acc[4][4] = {};
  for (int k0 = 0; k0 < K; k0 += 16) {
    float4 a = {0,0,0,0}, w = {0,0,0,0};
    int gm = m0 + lrow;
    if (gm < M) a = *(const float4*)(A + (size_t)gm*K + k0 + lcol);
    int gn = n0 + lrow;
    if (gn < N) w = *(const float4*)(W + (size_t)gn*K + k0 + lcol);
    __syncthreads();
    As[lcol+0][lrow]=a.x; As[lcol+1][lrow]=a.y; As[lcol+2][lrow]=a.z; As[lcol+3][lrow]=a.w;
    Ws[lcol+0][lrow]=w.x; Ws[lcol+1][lrow]=w.y; Ws[lcol+2][lrow]=w.z; Ws[lcol+3][lrow]=w.w;
    __syncthreads();
#pragma unroll
    for (int kk=0;kk<16;++kk){
      const float4 av = *(const float4*)&As[kk][ty*4];
      const float4 wv = *(const float4*)&Ws[kk][tx*4];
      float a_[4]={av.x,av.y,av.z,av.w};
      float w_[4]={wv.x,wv.y,wv.z,wv.w};
#pragma unroll
      for (int i=0;i<4;++i)
#pragma unroll
        for (int j=0;j<4;++j) acc[i][j] += a_[i]*w_[j];
    }
  }
#pragma unroll
  for (int i=0;i<4;++i){
    int gm = m0 + ty*4 + i;
    if (gm >= M) continue;
#pragma unroll
    for (int j=0;j<4;++j){
      int gn = n0 + tx*4 + j;
      if (gn >= N) continue;
      float v = acc[i][j];
      if (b1) v += b1[gn];
      if (b2) v += b2[gn];
      if (relu) v = fmaxf(v, 0.f);
      C[(size_t)gm*ldc + coff + gn] = v;
    }
  }
}

// ---------------- sequential LSTM (input-side GEMM precomputed into `pre`)
// grid: BATCH blocks; block: 768 threads (2 threads per gate).
// Depth-4 software prefetch of the pre row hides HBM latency (~900cy) under
// ~4 steps of compute; fast sigmoid/tanh via v_exp + v_rcp.
__global__ __launch_bounds__(768)
void lstm_kernel(const float* __restrict__ pre, const float* __restrict__ w_hh,
                 float* __restrict__ hout)
{
  const int b = blockIdx.x;
  const int tid = threadIdx.x;
  const int g = tid >> 1, half = tid & 1;
  float w[48];
  {
    const float* wp = w_hh + g*96 + half*48;
#pragma unroll
    for (int j=0;j<48;j+=4){
      float4 t = *(const float4*)(wp + j);
      w[j]=t.x; w[j+1]=t.y; w[j+2]=t.z; w[j+3]=t.w;
    }
  }
  __shared__ float h_lds[96];
  __shared__ float gate_lds[384];
  float c = 0.f;
  if (tid < 96) h_lds[tid] = 0.f;
  __syncthreads();
  const float* prow = pre + (size_t)b*T_SEQ*G4 + g;   // per-thread gate column
  float* hrow = hout + (size_t)b*T_SEQ*HID;
  float pf[4];
#pragma unroll
  for (int i=0;i<4;++i) pf[i] = prow[(size_t)i*G4];
  for (int tb=0; tb<T_SEQ; tb+=4){
#pragma unroll
    for (int u=0; u<4; ++u){
      const int t = tb + u;
      const float pcur = pf[u];
      int tn = t + 4; if (tn > T_SEQ-1) tn = T_SEQ-1;
      pf[u] = prow[(size_t)tn*G4];          // prefetch 4 steps ahead
      const float* hb = h_lds + half*48;
      float a0=0.f,a1=0.f,a2=0.f,a3=0.f;
#pragma unroll
      for (int j=0;j<48;j+=4){
        a0 += w[j]*hb[j]; a1 += w[j+1]*hb[j+1];
        a2 += w[j+2]*hb[j+2]; a3 += w[j+3]*hb[j+3];
      }
      float acc = (a0+a1)+(a2+a3);
      acc += __shfl_xor(acc, 1, 64);
      if (half == 0) gate_lds[g] = acc + pcur;
      __syncthreads();
      if (tid < 96){
        float ig = gate_lds[tid], fg = gate_lds[96+tid];
        float gg = gate_lds[192+tid], og = gate_lds[288+tid];
        float is = fast_sig(ig);
        float fs = fast_sig(fg);
        float gt = fast_tanh(gg);
        float os = fast_sig(og);
        c = fs*c + is*gt;
        float hv = os * fast_tanh(c);
        h_lds[tid] = hv;
        hrow[t*HID + tid] = hv;
      }
      __syncthreads();
    }
  }
}

// ---------------- attention over full rows (sparse top-k optional)
// qkv layout: [B*T][288] (q|k|v). One wave per q-row, 8 rows/WG share staged K/V.
__global__ __launch_bounds__(512)
void attn_kernel(const float* __restrict__ qkv, float* __restrict__ out, int sparse)
{
  __shared__ float kl[24][260];
  const int tid = threadIdx.x;
  const int wave = tid >> 6, lane = tid & 63;
  const int bh = blockIdx.x >> 7;            // 128 blocks per (b,h)
  const int b = bh >> 2, h = bh & 3;
  const int tq = ((blockIdx.x & 127) << 3) + wave;
  const size_t base = (size_t)b * T_SEQ;
  const int hoff = h * HDIM;
  float q[24];
  {
    const float* qp = qkv + (base + tq)*QKV_LD + hoff;
#pragma unroll
    for (int d4=0; d4<6; ++d4){
      float4 t = *(const float4*)(qp + d4*4);
      q[d4*4]=t.x; q[d4*4+1]=t.y; q[d4*4+2]=t.z; q[d4*4+3]=t.w;
    }
  }
  float sc[16];
  // pass A: scores (lane owns s = c*256 + lane*4 + j)
  for (int c=0;c<4;++c){
    __syncthreads();
#pragma unroll
    for (int rep=0;rep<3;++rep){
      int p = rep*512 + tid;
      int sl = p/6, d4 = p - sl*6;
      const float4 kv = *(const float4*)(qkv + (base + (c<<8) + sl)*QKV_LD + 96 + hoff + d4*4);
      kl[d4*4+0][sl]=kv.x; kl[d4*4+1][sl]=kv.y; kl[d4*4+2][sl]=kv.z; kl[d4*4+3][sl]=kv.w;
    }
    __syncthreads();
    float a0=0.f,a1=0.f,a2=0.f,a3=0.f;
#pragma unroll
    for (int d=0; d<24; ++d){
      const float4 kd = *(const float4*)&kl[d][lane*4];
      a0 += q[d]*kd.x; a1 += q[d]*kd.y; a2 += q[d]*kd.z; a3 += q[d]*kd.w;
    }
    sc[c*4+0]=a0*SCALE; sc[c*4+1]=a1*SCALE; sc[c*4+2]=a2*SCALE; sc[c*4+3]=a3*SCALE;
  }
  // softmax (+ exact top-k mask)
  float m_loc = sc[0];
#pragma unroll
  for (int i=1;i<16;++i) m_loc = fmaxf(m_loc, sc[i]);
  const float m = wred_max(m_loc);
  float sum_loc = 0.f;
  if (sparse){
    unsigned u[16];
#pragma unroll
    for (int i=0;i<16;++i) u[i] = fmono(sc[i]);
    unsigned prefix = 0;
    for (int bit=31; bit>=0; --bit){
      unsigned test = prefix | (1u<<bit);
      int cnt = 0;
#pragma unroll
      for (int i=0;i<16;++i) cnt += (u[i] >= test) ? 1 : 0;
      cnt = wred_sumi(cnt);
      if (cnt >= KKEEP) prefix = test;
    }
#pragma unroll
    for (int i=0;i<16;++i){
      float e = (u[i] >= prefix) ? __expf(sc[i]-m) : 0.f;
      sc[i] = e; sum_loc += e;
    }
  } else {
#pragma unroll
    for (int i=0;i<16;++i){
      float e = __expf(sc[i]-m);
      sc[i] = e; sum_loc += e;
    }
  }
  const float inv = 1.f / wred_sum(sum_loc);
#pragma unroll
  for (int i=0;i<16;++i) sc[i] *= inv;
  // pass B: PV
  float acc[24] = {};
  for (int c=0;c<4;++c){
    __syncthreads();
#pragma unroll
    for (int rep=0;rep<3;++rep){
      int p = rep*512 + tid;
      int sl = p/6, d4 = p - sl*6;
      const float4 vv = *(const float4*)(qkv + (base + (c<<8) + sl)*QKV_LD + 192 + hoff + d4*4);
      kl[d4*4+0][sl]=vv.x; kl[d4*4+1][sl]=vv.y; kl[d4*4+2][sl]=vv.z; kl[d4*4+3][sl]=vv.w;
    }
    __syncthreads();
    const float w0=sc[c*4], w1=sc[c*4+1], w2=sc[c*4+2], w3=sc[c*4+3];
#pragma unroll
    for (int d=0; d<24; ++d){
      const float4 vd = *(const float4*)&kl[d][lane*4];
      acc[d] += w0*vd.x + w1*vd.y + w2*vd.z + w3*vd.w;
    }
  }
#pragma unroll
  for (int d=0; d<24; ++d) acc[d] = wred_sum(acc[d]);
  if (lane == 0){
    float* op = out + (base + tq)*HID + hoff;
#pragma unroll
    for (int d4=0; d4<6; ++d4){
      float4 t = {acc[d4*4], acc[d4*4+1], acc[d4*4+2], acc[d4*4+3]};
      *(float4*)(op + d4*4) = t;
    }
  }
}

// ---------------- dense attention for t = T-1 only (encoder 2): 64 rows, 1 wave each
__global__ __launch_bounds__(64)
void attn_last_kernel(const float* __restrict__ qkv, float* __restrict__ out)
{
  const int bh = blockIdx.x, b = bh>>2, h = bh&3;
  const int lane = threadIdx.x;
  const size_t base = (size_t)b*T_SEQ;
  const int hoff = h*HDIM;
  float q[24];
  {
    const float* qp = qkv + (base + T_SEQ-1)*QKV_LD + hoff;
#pragma unroll
    for (int d4=0; d4<6; ++d4){
      float4 t = *(const float4*)(qp + d4*4);
      q[d4*4]=t.x; q[d4*4+1]=t.y; q[d4*4+2]=t.z; q[d4*4+3]=t.w;
    }
  }
  float sc[16];
#pragma unroll 4
  for (int i=0;i<16;++i){
    const float* kp = qkv + (base + i*64 + lane)*QKV_LD + 96 + hoff;
    float a = 0.f;
#pragma unroll
    for (int d4=0; d4<6; ++d4){
      float4 kv = *(const float4*)(kp + d4*4);
      a += q[d4*4]*kv.x + q[d4*4+1]*kv.y + q[d4*4+2]*kv.z + q[d4*4+3]*kv.w;
    }
    sc[i] = a*SCALE;
  }
  float m_loc = sc[0];
#pragma unroll
  for (int i=1;i<16;++i) m_loc = fmaxf(m_loc, sc[i]);
  const float m = wred_max(m_loc);
  float sum_loc = 0.f;
#pragma unroll
  for (int i=0;i<16;++i){ sc[i] = __expf(sc[i]-m); sum_loc += sc[i]; }
  const float inv = 1.f / wred_sum(sum_loc);
  float acc[24] = {};
#pragma unroll 4
  for (int i=0;i<16;++i){
    const float* vp = qkv + (base + i*64 + lane)*QKV_LD + 192 + hoff;
    const float wgt = sc[i]*inv;
#pragma unroll
    for (int d4=0; d4<6; ++d4){
      float4 vv = *(const float4*)(vp + d4*4);
      acc[d4*4]   += wgt*vv.x; acc[d4*4+1] += wgt*vv.y;
      acc[d4*4+2] += wgt*vv.z; acc[d4*4+3] += wgt*vv.w;
    }
  }
#pragma unroll
  for (int d=0; d<24; ++d) acc[d] = wred_sum(acc[d]);
  if (lane == 0){
    float* op = out + (base + T_SEQ-1)*HID + hoff;
#pragma unroll
    for (int d4=0; d4<6; ++d4){
      float4 t = {acc[d4*4], acc[d4*4+1], acc[d4*4+2], acc[d4*4+3]};
      *(float4*)(op + d4*4) = t;
    }
  }
}

// ---------------- out = LayerNorm(x + y) * w + b ; one wave per 96-wide row
__global__ __launch_bounds__(256)
void resln_kernel(const float* __restrict__ x, const float* __restrict__ y,
                  const float* __restrict__ w, const float* __restrict__ bb,
                  float* __restrict__ out)
{
  const int row = blockIdx.x*4 + (threadIdx.x>>6);
  const int lane = threadIdx.x & 63;
  const float* xr = x + (size_t)row*HID;
  const float* yr = y + (size_t)row*HID;
  float v0 = xr[lane] + yr[lane];
  float v1 = (lane < 32) ? (xr[64+lane] + yr[64+lane]) : 0.f;
  float mu = wred_sum(v0+v1) * (1.f/96.f);
  float d0 = v0-mu, d1 = (lane<32) ? (v1-mu) : 0.f;
  float var = wred_sum(d0*d0 + d1*d1) * (1.f/96.f);
  float rs = rsqrtf(var + 1e-5f);
  float* orow = out + (size_t)row*HID;
  orow[lane] = d0*rs*w[lane] + bb[lane];
  if (lane < 32) orow[64+lane] = d1*rs*w[64+lane] + bb[64+lane];
}

// ---------------- encoder-2 tail at t=T-1 only: proj+LN1+FF+LN2+fc
__device__ __forceinline__ float block_sum_192(float v, float* red){
  v = wred_sum(v);
  const int tid = threadIdx.x;
  if ((tid & 63) == 0) red[tid>>6] = v;
  __syncthreads();
  float r = red[0]+red[1]+red[2];
  __syncthreads();
  return r;
}

__global__ __launch_bounds__(192)
void tail_kernel(const float* __restrict__ xin, const float* __restrict__ mha,
                 const float* __restrict__ out_w, const float* __restrict__ out_b,
                 const float* __restrict__ l1_w, const float* __restrict__ l1_b,
                 const float* __restrict__ l2_w, const float* __restrict__ l2_b,
                 const float* __restrict__ ln1w, const float* __restrict__ ln1b,
                 const float* __restrict__ ln2w, const float* __restrict__ ln2b,
                 const float* __restrict__ fcw, const float* __restrict__ fcb,
                 float* __restrict__ outp)
{
  const int b = blockIdx.x, tid = threadIdx.x;
  __shared__ float y[96], f1[192], mrow[96], red[3];
  const size_t row = ((size_t)b*T_SEQ + T_SEQ-1)*HID;
  if (tid < 96) mrow[tid] = mha[row + tid];
  __syncthreads();
  float r = 0.f;
  if (tid < 96){
    float p = out_b[tid];
    const float* wr = out_w + tid*96;
#pragma unroll 4
    for (int d=0; d<96; ++d) p += mrow[d]*wr[d];
    r = xin[row + tid] + p;
  }
  float mu = block_sum_192(tid<96 ? r : 0.f, red) * (1.f/96.f);
  float dv = tid<96 ? r-mu : 0.f;
  float var = block_sum_192(dv*dv, red) * (1.f/96.f);
  float rs = rsqrtf(var + 1e-5f);
  if (tid < 96) y[tid] = dv*rs*ln1w[tid] + ln1b[tid];
  __syncthreads();
  {
    float a = l1_b[tid];
    const float* wr = l1_w + tid*96;
#pragma unroll 4
    for (int d=0; d<96; ++d) a += y[d]*wr[d];
    f1[tid] = fmaxf(a, 0.f);
  }
  __syncthreads();
  float r2 = 0.f;
  if (tid < 96){
    float a = l2_b[tid];
    const float* wr = l2_w + tid*192;
#pragma unroll 4
    for (int d=0; d<192; ++d) a += f1[d]*wr[d];
    r2 = y[tid] + a;
  }
  float mu2 = block_sum_192(tid<96 ? r2 : 0.f, red) * (1.f/96.f);
  float dv2 = tid<96 ? r2-mu2 : 0.f;
  float var2 = block_sum_192(dv2*dv2, red) * (1.f/96.f);
  float rs2 = rsqrtf(var2 + 1e-5f);
  float z = tid<96 ? (dv2*rs2*ln2w[tid] + ln2b[tid]) : 0.f;
  float tot = block_sum_192(tid<96 ? z*fcw[tid] : 0.f, red);
  if (tid == 0) outp[b] = tot + fcb[0];
}

extern "C" void kernel_launch(void* const* d_in, const int* in_sizes, int n_in,
                              void* d_out, int out_size, void* d_ws, size_t ws_size,
                              hipStream_t stream)
{
  const float* x     = (const float*)d_in[0];
  const float* w_ih0 = (const float*)d_in[1];
  const float* w_hh0 = (const float*)d_in[2];
  const float* b_ih0 = (const float*)d_in[3];
  const float* b_hh0 = (const float*)d_in[4];
  const float* w_ih1 = (const float*)d_in[5];
  const float* w_hh1 = (const float*)d_in[6];
  const float* b_ih1 = (const float*)d_in[7];
  const float* b_hh1 = (const float*)d_in[8];
  const float* qw = (const float*)d_in[9];
  const float* kw = (const float*)d_in[10];
  const float* vw = (const float*)d_in[11];
  const float* ow = (const float*)d_in[12];
  const float* enc_in_w  = (const float*)d_in[13];
  const float* enc_in_b  = (const float*)d_in[14];
  const float* enc_out_w = (const float*)d_in[15];
  const float* enc_out_b = (const float*)d_in[16];
  const float* enc_l1_w  = (const float*)d_in[17];
  const float* enc_l1_b  = (const float*)d_in[18];
  const float* enc_l2_w  = (const float*)d_in[19];
  const float* enc_l2_b  = (const float*)d_in[20];
  const float* enc_ln1_w = (const float*)d_in[21];
  const float* enc_ln1_b = (const float*)d_in[22];
  const float* enc_ln2_w = (const float*)d_in[23];
  const float* enc_ln2_b = (const float*)d_in[24];
  const float* fc_w = (const float*)d_in[25];
  const float* fc_b = (const float*)d_in[26];
  float* outp = (float*)d_out;

  float* ws = (float*)d_ws;
  const size_t MT = (size_t)BATCH*T_SEQ;   // 16384
  float* pre  = ws;                        // 16384*384 (also qkv[288] / ff1[192])
  float* bufA = pre  + MT*G4;
  float* bufB = bufA + MT*HID;
  float* bufC = bufB + MT*HID;

  const int M = (int)MT;
  auto gemm = [&](const float* A, const float* W, const float* bb1, const float* bb2,
                  float* C, int N, int K, int ldc, int coff, int relu){
    dim3 grid((N+63)/64, M/64);
    gemm_kernel<<<grid, dim3(256), 0, stream>>>(A, W, bb1, bb2, C, M, N, K, ldc, coff, relu);
  };

  // LSTM layer 0
  gemm(x, w_ih0, b_ih0, b_hh0, pre, 384, 64, 384, 0, 0);
  lstm_kernel<<<dim3(BATCH), dim3(768), 0, stream>>>(pre, w_hh0, bufA);
  // LSTM layer 1
  gemm(bufA, w_ih1, b_ih1, b_hh1, pre, 384, 96, 384, 0, 0);
  lstm_kernel<<<dim3(BATCH), dim3(768), 0, stream>>>(pre, w_hh1, bufB);
  // sparse attention
  gemm(bufB, qw, nullptr, nullptr, pre, 96, 96, QKV_LD, 0,   0);
  gemm(bufB, kw, nullptr, nullptr, pre, 96, 96, QKV_LD, 96,  0);
  gemm(bufB, vw, nullptr, nullptr, pre, 96, 96, QKV_LD, 192, 0);
  attn_kernel<<<dim3(8192), dim3(512), 0, stream>>>(pre, bufA, 1);
  gemm(bufA, ow, nullptr, nullptr, bufB, 96, 96, 96, 0, 0);
  // encoder layer 0 (full)
  gemm(bufB, enc_in_w, enc_in_b, nullptr, pre, 288, 96, QKV_LD, 0, 0);
  attn_kernel<<<dim3(8192), dim3(512), 0, stream>>>(pre, bufA, 0);
  gemm(bufA, enc_out_w, enc_out_b, nullptr, bufC, 96, 96, 96, 0, 0);
  resln_kernel<<<dim3(4096), dim3(256), 0, stream>>>(bufB, bufC, enc_ln1_w, enc_ln1_b, bufB);
  gemm(bufB, enc_l1_w, enc_l1_b, nullptr, pre, 192, 96, 192, 0, 1);
  gemm(pre, enc_l2_w, enc_l2_b, nullptr, bufC, 96, 192, 96, 0, 0);
  resln_kernel<<<dim3(4096), dim3(256), 0, stream>>>(bufB, bufC, enc_ln2_w, enc_ln2_b, bufB);
  // encoder layer 1 — only t = T-1 reaches the output head
  gemm(bufB, enc_in_w + 288*96, enc_in_b + 288, nullptr, pre, 288, 96, QKV_LD, 0, 0);
  attn_last_kernel<<<dim3(64), dim3(64), 0, stream>>>(pre, bufA);
  tail_kernel<<<dim3(BATCH), dim3(192), 0, stream>>>(
      bufB, bufA,
      enc_out_w + 96*96, enc_out_b + 96,
      enc_l1_w + 192*96, enc_l1_b + 192,
      enc_l2_w + 96*192, enc_l2_b + 96,
      enc_ln1_w + 96, enc_ln1_b + 96,
      enc_ln2_w + 96, enc_ln2_b + 96,
      fc_w, fc_b, outp);
}

// Round 3
// 2221.603 us; speedup vs baseline: 1.4162x; 1.0169x over previous
//
#include <hip/hip_runtime.h>
#include <cstdint>
#include <cmath>

#define T_SEQ 1024
#define BATCH 16
#define HID 96
#define G4 384
#define QKV_LD 288
#define HDIM 24
#define KKEEP 512
#define SCALE 0.20412414523193154f  // 1/sqrt(24)
#define L2E 1.4426950408889634f     // log2(e)

__device__ __forceinline__ float wred_sum(float v){
#pragma unroll
  for (int o=32;o;o>>=1) v += __shfl_xor(v,o,64);
  return v;
}
__device__ __forceinline__ float wred_max(float v){
#pragma unroll
  for (int o=32;o;o>>=1) v = fmaxf(v,__shfl_xor(v,o,64));
  return v;
}
__device__ __forceinline__ int wred_sumi(int v){
#pragma unroll
  for (int o=32;o;o>>=1) v += __shfl_xor(v,o,64);
  return v;
}
__device__ __forceinline__ unsigned fmono(float f){
  unsigned u = __float_as_uint(f);
  return (u & 0x80000000u) ? ~u : (u | 0x80000000u);
}

// ---------------- generic tiled GEMM: C[m, coff+n] = act(A[M,K] @ W[N,K]^T + b1 + b2)
__global__ __launch_bounds__(256)
void gemm_kernel(const float* __restrict__ A, const float* __restrict__ W,
                 const float* __restrict__ b1, const float* __restrict__ b2,
                 float* __restrict__ C, int M, int N, int K,
                 int ldc, int coff, int relu)
{
  __shared__ float As[16][68];
  __shared__ float Ws[16][68];
  const int tid = threadIdx.x;
  const int tx = tid & 15, ty = tid >> 4;
  const int m0 = blockIdx.y * 64, n0 = blockIdx.x * 64;
  const int lrow = tid >> 2, lcol = (tid & 3) * 4;
  float acc[4][4] = {};
  for (int k0 = 0; k0 < K; k0 += 16) {
    float4 a = {0,0,0,0}, w = {0,0,0,0};
    int gm = m0 + lrow;
    if (gm < M) a = *(const float4*)(A + (size_t)gm*K + k0 + lcol);
    int gn = n0 + lrow;
    if (gn < N) w = *(const float4*)(W + (size_t)gn*K + k0 + lcol);
    __syncthreads();
    As[lcol+0][lrow]=a.x; As[lcol+1][lrow]=a.y; As[lcol+2][lrow]=a.z; As[lcol+3][lrow]=a.w;
    Ws[lcol+0][lrow]=w.x; Ws[lcol+1][lrow]=w.y; Ws[lcol+2][lrow]=w.z; Ws[lcol+3][lrow]=w.w;
    __syncthreads();
#pragma unroll
    for (int kk=0;kk<16;++kk){
      const float4 av = *(const float4*)&As[kk][ty*4];
      const float4 wv = *(const float4*)&Ws[kk][tx*4];
      float a_[4]={av.x,av.y,av.z,av.w};
      float w_[4]={wv.x,wv.y,wv.z,wv.w};
#pragma unroll
      for (int i=0;i<4;++i)
#pragma unroll
        for (int j=0;j<4;++j) acc[i][j] += a_[i]*w_[j];
    }
  }
#pragma unroll
  for (int i=0;i<4;++i){
    int gm = m0 + ty*4 + i;
    if (gm >= M) continue;
#pragma unroll
    for (int j=0;j<4;++j){
      int gn = n0 + tx*4 + j;
      if (gn >= N) continue;
      float v = acc[i][j];
      if (b1) v += b1[gn];
      if (b2) v += b2[gn];
      if (relu) v = fmaxf(v, 0.f);
      C[(size_t)gm*ldc + coff + gn] = v;
    }
  }
}

// ---------------- sequential LSTM, 1 barrier per step.
// tid = j*8 + gid*2 + half: column j (0..95), gate gid (0..3: i,f,g,o), half (0..1).
// Each thread: 48-MAC half-dot; shfl_xor(1) combines halves; each lane applies
// its OWN gate's activation (branchless unified form); 3 shfl_xor gather the
// 4 activations per column; c/h updated redundantly per column (no LDS pass).
__global__ __launch_bounds__(768)
void lstm_kernel(const float* __restrict__ pre, const float* __restrict__ w_hh,
                 float* __restrict__ hout)
{
  const int b = blockIdx.x;
  const int tid = threadIdx.x;
  const int half = tid & 1, gid = (tid >> 1) & 3, j = tid >> 3;
  const int grow = gid * 96 + j;           // gate row in [0,384)
  float w[48];
  {
    const float* wp = w_hh + grow*96 + half*48;
#pragma unroll
    for (int k=0;k<48;k+=4){
      float4 t = *(const float4*)(wp + k);
      w[k]=t.x; w[k+1]=t.y; w[k+2]=t.z; w[k+3]=t.w;
    }
  }
  // unified activation constants: act = A + B * rcp(1 + exp2(C*x))
  // sigmoid: A=0, B=1, C=-log2e ; tanh (gid==2): A=1, B=-2, C=+2*log2e
  const float Ac = (gid==2) ? 1.f : 0.f;
  const float Bc = (gid==2) ? -2.f : 1.f;
  const float Cc = (gid==2) ? 2.f*L2E : -L2E;
  const bool g0 = (gid==0), g1 = (gid==1), g2 = (gid==2), g3 = (gid==3);

  __shared__ float h_lds[96];
  float c = 0.f;
  if (tid < 96) h_lds[tid] = 0.f;
  __syncthreads();

  const float* prow = pre + (size_t)b*T_SEQ*G4 + grow;
  float* hrow = hout + (size_t)b*T_SEQ*HID;
  float pf[4];
#pragma unroll
  for (int i=0;i<4;++i) pf[i] = prow[(size_t)i*G4];

  for (int tb=0; tb<T_SEQ; tb+=4){
#pragma unroll
    for (int u=0; u<4; ++u){
      const int t = tb + u;
      const float pcur = pf[u];
      int tn = t + 4; if (tn > T_SEQ-1) tn = T_SEQ-1;
      pf[u] = prow[(size_t)tn*G4];          // prefetch 4 steps ahead
      const float* hb = h_lds + half*48;    // broadcast reads (2 addrs/wave)
      float a0=0.f,a1=0.f,a2=0.f,a3=0.f;
#pragma unroll
      for (int k=0;k<48;k+=4){
        a0 += w[k]*hb[k];   a1 += w[k+1]*hb[k+1];
        a2 += w[k+2]*hb[k+2]; a3 += w[k+3]*hb[k+3];
      }
      float acc = (a0+a1)+(a2+a3);
      const float full = acc + __shfl_xor(acc, 1, 64) + pcur;
      // own-gate activation
      const float act = fmaf(Bc, __builtin_amdgcn_rcpf(1.f + __builtin_amdgcn_exp2f(Cc*full)), Ac);
      // gather the other three gates of this column (gid = lane bits 1..2)
      const float x1 = __shfl_xor(act, 2, 64);  // gid^1
      const float x2 = __shfl_xor(act, 4, 64);  // gid^2
      const float x3 = __shfl_xor(act, 6, 64);  // gid^3
      const float iv = g0?act : g1?x1 : g2?x2 : x3;
      const float fv = g1?act : g0?x1 : g3?x2 : x3;
      const float gv = g2?act : g3?x1 : g0?x2 : x3;
      const float ov = g3?act : g2?x1 : g1?x2 : x3;
      c = fmaf(fv, c, iv*gv);
      const float th = fmaf(-2.f, __builtin_amdgcn_rcpf(1.f + __builtin_amdgcn_exp2f(c*(2.f*L2E))), 1.f);
      const float hv = ov*th;
      if ((tid & 7) == 0){
        h_lds[j] = hv;
        hrow[t*HID + j] = hv;
      }
      __syncthreads();
    }
  }
}

// ---------------- attention over full rows (sparse top-k optional)
// qkv layout: [B*T][288] (q|k|v). One wave per q-row, 8 rows/WG share staged K/V.
__global__ __launch_bounds__(512)
void attn_kernel(const float* __restrict__ qkv, float* __restrict__ out, int sparse)
{
  __shared__ float kl[24][260];
  const int tid = threadIdx.x;
  const int wave = tid >> 6, lane = tid & 63;
  const int bh = blockIdx.x >> 7;            // 128 blocks per (b,h)
  const int b = bh >> 2, h = bh & 3;
  const int tq = ((blockIdx.x & 127) << 3) + wave;
  const size_t base = (size_t)b * T_SEQ;
  const int hoff = h * HDIM;
  float q[24];
  {
    const float* qp = qkv + (base + tq)*QKV_LD + hoff;
#pragma unroll
    for (int d4=0; d4<6; ++d4){
      float4 t = *(const float4*)(qp + d4*4);
      q[d4*4]=t.x; q[d4*4+1]=t.y; q[d4*4+2]=t.z; q[d4*4+3]=t.w;
    }
  }
  float sc[16];
  // pass A: scores (lane owns s = c*256 + lane*4 + j)
  for (int c=0;c<4;++c){
    __syncthreads();
#pragma unroll
    for (int rep=0;rep<3;++rep){
      int p = rep*512 + tid;
      int sl = p/6, d4 = p - sl*6;
      const float4 kv = *(const float4*)(qkv + (base + (c<<8) + sl)*QKV_LD + 96 + hoff + d4*4);
      kl[d4*4+0][sl]=kv.x; kl[d4*4+1][sl]=kv.y; kl[d4*4+2][sl]=kv.z; kl[d4*4+3][sl]=kv.w;
    }
    __syncthreads();
    float a0=0.f,a1=0.f,a2=0.f,a3=0.f;
#pragma unroll
    for (int d=0; d<24; ++d){
      const float4 kd = *(const float4*)&kl[d][lane*4];
      a0 += q[d]*kd.x; a1 += q[d]*kd.y; a2 += q[d]*kd.z; a3 += q[d]*kd.w;
    }
    sc[c*4+0]=a0*SCALE; sc[c*4+1]=a1*SCALE; sc[c*4+2]=a2*SCALE; sc[c*4+3]=a3*SCALE;
  }
  // softmax (+ exact top-k mask)
  float m_loc = sc[0];
#pragma unroll
  for (int i=1;i<16;++i) m_loc = fmaxf(m_loc, sc[i]);
  const float m = wred_max(m_loc);
  float sum_loc = 0.f;
  if (sparse){
    unsigned u[16];
#pragma unroll
    for (int i=0;i<16;++i) u[i] = fmono(sc[i]);
    unsigned prefix = 0;
    for (int bit=31; bit>=0; --bit){
      unsigned test = prefix | (1u<<bit);
      int cnt = 0;
#pragma unroll
      for (int i=0;i<16;++i) cnt += (u[i] >= test) ? 1 : 0;
      cnt = wred_sumi(cnt);
      if (cnt >= KKEEP) prefix = test;
    }
#pragma unroll
    for (int i=0;i<16;++i){
      float e = (u[i] >= prefix) ? __expf(sc[i]-m) : 0.f;
      sc[i] = e; sum_loc += e;
    }
  } else {
#pragma unroll
    for (int i=0;i<16;++i){
      float e = __expf(sc[i]-m);
      sc[i] = e; sum_loc += e;
    }
  }
  const float inv = 1.f / wred_sum(sum_loc);
#pragma unroll
  for (int i=0;i<16;++i) sc[i] *= inv;
  // pass B: PV
  float acc[24] = {};
  for (int c=0;c<4;++c){
    __syncthreads();
#pragma unroll
    for (int rep=0;rep<3;++rep){
      int p = rep*512 + tid;
      int sl = p/6, d4 = p - sl*6;
      const float4 vv = *(const float4*)(qkv + (base + (c<<8) + sl)*QKV_LD + 192 + hoff + d4*4);
      kl[d4*4+0][sl]=vv.x; kl[d4*4+1][sl]=vv.y; kl[d4*4+2][sl]=vv.z; kl[d4*4+3][sl]=vv.w;
    }
    __syncthreads();
    const float w0=sc[c*4], w1=sc[c*4+1], w2=sc[c*4+2], w3=sc[c*4+3];
#pragma unroll
    for (int d=0; d<24; ++d){
      const float4 vd = *(const float4*)&kl[d][lane*4];
      acc[d] += w0*vd.x + w1*vd.y + w2*vd.z + w3*vd.w;
    }
  }
#pragma unroll
  for (int d=0; d<24; ++d) acc[d] = wred_sum(acc[d]);
  if (lane == 0){
    float* op = out + (base + tq)*HID + hoff;
#pragma unroll
    for (int d4=0; d4<6; ++d4){
      float4 t = {acc[d4*4], acc[d4*4+1], acc[d4*4+2], acc[d4*4+3]};
      *(float4*)(op + d4*4) = t;
    }
  }
}

// ---------------- dense attention for t = T-1 only (encoder 2): 64 rows, 1 wave each
__global__ __launch_bounds__(64)
void attn_last_kernel(const float* __restrict__ qkv, float* __restrict__ out)
{
  const int bh = blockIdx.x, b = bh>>2, h = bh&3;
  const int lane = threadIdx.x;
  const size_t base = (size_t)b*T_SEQ;
  const int hoff = h*HDIM;
  float q[24];
  {
    const float* qp = qkv + (base + T_SEQ-1)*QKV_LD + hoff;
#pragma unroll
    for (int d4=0; d4<6; ++d4){
      float4 t = *(const float4*)(qp + d4*4);
      q[d4*4]=t.x; q[d4*4+1]=t.y; q[d4*4+2]=t.z; q[d4*4+3]=t.w;
    }
  }
  float sc[16];
#pragma unroll 4
  for (int i=0;i<16;++i){
    const float* kp = qkv + (base + i*64 + lane)*QKV_LD + 96 + hoff;
    float a = 0.f;
#pragma unroll
    for (int d4=0; d4<6; ++d4){
      float4 kv = *(const float4*)(kp + d4*4);
      a += q[d4*4]*kv.x + q[d4*4+1]*kv.y + q[d4*4+2]*kv.z + q[d4*4+3]*kv.w;
    }
    sc[i] = a*SCALE;
  }
  float m_loc = sc[0];
#pragma unroll
  for (int i=1;i<16;++i) m_loc = fmaxf(m_loc, sc[i]);
  const float m = wred_max(m_loc);
  float sum_loc = 0.f;
#pragma unroll
  for (int i=0;i<16;++i){ sc[i] = __expf(sc[i]-m); sum_loc += sc[i]; }
  const float inv = 1.f / wred_sum(sum_loc);
  float acc[24] = {};
#pragma unroll 4
  for (int i=0;i<16;++i){
    const float* vp = qkv + (base + i*64 + lane)*QKV_LD + 192 + hoff;
    const float wgt = sc[i]*inv;
#pragma unroll
    for (int d4=0; d4<6; ++d4){
      float4 vv = *(const float4*)(vp + d4*4);
      acc[d4*4]   += wgt*vv.x; acc[d4*4+1] += wgt*vv.y;
      acc[d4*4+2] += wgt*vv.z; acc[d4*4+3] += wgt*vv.w;
    }
  }
#pragma unroll
  for (int d=0; d<24; ++d) acc[d] = wred_sum(acc[d]);
  if (lane == 0){
    float* op = out + (base + T_SEQ-1)*HID + hoff;
#pragma unroll
    for (int d4=0; d4<6; ++d4){
      float4 t = {acc[d4*4], acc[d4*4+1], acc[d4*4+2], acc[d4*4+3]};
      *(float4*)(op + d4*4) = t;
    }
  }
}

// ---------------- out = LayerNorm(x + y) * w + b ; one wave per 96-wide row
__global__ __launch_bounds__(256)
void resln_kernel(const float* __restrict__ x, const float* __restrict__ y,
                  const float* __restrict__ w, const float* __restrict__ bb,
                  float* __restrict__ out)
{
  const int row = blockIdx.x*4 + (threadIdx.x>>6);
  const int lane = threadIdx.x & 63;
  const float* xr = x + (size_t)row*HID;
  const float* yr = y + (size_t)row*HID;
  float v0 = xr[lane] + yr[lane];
  float v1 = (lane < 32) ? (xr[64+lane] + yr[64+lane]) : 0.f;
  float mu = wred_sum(v0+v1) * (1.f/96.f);
  float d0 = v0-mu, d1 = (lane<32) ? (v1-mu) : 0.f;
  float var = wred_sum(d0*d0 + d1*d1) * (1.f/96.f);
  float rs = rsqrtf(var + 1e-5f);
  float* orow = out + (size_t)row*HID;
  orow[lane] = d0*rs*w[lane] + bb[lane];
  if (lane < 32) orow[64+lane] = d1*rs*w[64+lane] + bb[64+lane];
}

// ---------------- encoder-2 tail at t=T-1 only: proj+LN1+FF+LN2+fc
__device__ __forceinline__ float block_sum_192(float v, float* red){
  v = wred_sum(v);
  const int tid = threadIdx.x;
  if ((tid & 63) == 0) red[tid>>6] = v;
  __syncthreads();
  float r = red[0]+red[1]+red[2];
  __syncthreads();
  return r;
}

__global__ __launch_bounds__(192)
void tail_kernel(const float* __restrict__ xin, const float* __restrict__ mha,
                 const float* __restrict__ out_w, const float* __restrict__ out_b,
                 const float* __restrict__ l1_w, const float* __restrict__ l1_b,
                 const float* __restrict__ l2_w, const float* __restrict__ l2_b,
                 const float* __restrict__ ln1w, const float* __restrict__ ln1b,
                 const float* __restrict__ ln2w, const float* __restrict__ ln2b,
                 const float* __restrict__ fcw, const float* __restrict__ fcb,
                 float* __restrict__ outp)
{
  const int b = blockIdx.x, tid = threadIdx.x;
  __shared__ float y[96], f1[192], mrow[96], red[3];
  const size_t row = ((size_t)b*T_SEQ + T_SEQ-1)*HID;
  if (tid < 96) mrow[tid] = mha[row + tid];
  __syncthreads();
  float r = 0.f;
  if (tid < 96){
    float p = out_b[tid];
    const float* wr = out_w + tid*96;
#pragma unroll 4
    for (int d=0; d<96; ++d) p += mrow[d]*wr[d];
    r = xin[row + tid] + p;
  }
  float mu = block_sum_192(tid<96 ? r : 0.f, red) * (1.f/96.f);
  float dv = tid<96 ? r-mu : 0.f;
  float var = block_sum_192(dv*dv, red) * (1.f/96.f);
  float rs = rsqrtf(var + 1e-5f);
  if (tid < 96) y[tid] = dv*rs*ln1w[tid] + ln1b[tid];
  __syncthreads();
  {
    float a = l1_b[tid];
    const float* wr = l1_w + tid*96;
#pragma unroll 4
    for (int d=0; d<96; ++d) a += y[d]*wr[d];
    f1[tid] = fmaxf(a, 0.f);
  }
  __syncthreads();
  float r2 = 0.f;
  if (tid < 96){
    float a = l2_b[tid];
    const float* wr = l2_w + tid*192;
#pragma unroll 4
    for (int d=0; d<192; ++d) a += f1[d]*wr[d];
    r2 = y[tid] + a;
  }
  float mu2 = block_sum_192(tid<96 ? r2 : 0.f, red) * (1.f/96.f);
  float dv2 = tid<96 ? r2-mu2 : 0.f;
  float var2 = block_sum_192(dv2*dv2, red) * (1.f/96.f);
  float rs2 = rsqrtf(var2 + 1e-5f);
  float z = tid<96 ? (dv2*rs2*ln2w[tid] + ln2b[tid]) : 0.f;
  float tot = block_sum_192(tid<96 ? z*fcw[tid] : 0.f, red);
  if (tid == 0) outp[b] = tot + fcb[0];
}

extern "C" void kernel_launch(void* const* d_in, const int* in_sizes, int n_in,
                              void* d_out, int out_size, void* d_ws, size_t ws_size,
                              hipStream_t stream)
{
  const float* x     = (const float*)d_in[0];
  const float* w_ih0 = (const float*)d_in[1];
  const float* w_hh0 = (const float*)d_in[2];
  const float* b_ih0 = (const float*)d_in[3];
  const float* b_hh0 = (const float*)d_in[4];
  const float* w_ih1 = (const float*)d_in[5];
  const float* w_hh1 = (const float*)d_in[6];
  const float* b_ih1 = (const float*)d_in[7];
  const float* b_hh1 = (const float*)d_in[8];
  const float* qw = (const float*)d_in[9];
  const float* kw = (const float*)d_in[10];
  const float* vw = (const float*)d_in[11];
  const float* ow = (const float*)d_in[12];
  const float* enc_in_w  = (const float*)d_in[13];
  const float* enc_in_b  = (const float*)d_in[14];
  const float* enc_out_w = (const float*)d_in[15];
  const float* enc_out_b = (const float*)d_in[16];
  const float* enc_l1_w  = (const float*)d_in[17];
  const float* enc_l1_b  = (const float*)d_in[18];
  const float* enc_l2_w  = (const float*)d_in[19];
  const float* enc_l2_b  = (const float*)d_in[20];
  const float* enc_ln1_w = (const float*)d_in[21];
  const float* enc_ln1_b = (const float*)d_in[22];
  const float* enc_ln2_w = (const float*)d_in[23];
  const float* enc_ln2_b = (const float*)d_in[24];
  const float* fc_w = (const float*)d_in[25];
  const float* fc_b = (const float*)d_in[26];
  float* outp = (float*)d_out;

  float* ws = (float*)d_ws;
  const size_t MT = (size_t)BATCH*T_SEQ;   // 16384
  float* pre  = ws;                        // 16384*384 (also qkv[288] / ff1[192])
  float* bufA = pre  + MT*G4;
  float* bufB = bufA + MT*HID;
  float* bufC = bufB + MT*HID;

  const int M = (int)MT;
  auto gemm = [&](const float* A, const float* W, const float* bb1, const float* bb2,
                  float* C, int N, int K, int ldc, int coff, int relu){
    dim3 grid((N+63)/64, M/64);
    gemm_kernel<<<grid, dim3(256), 0, stream>>>(A, W, bb1, bb2, C, M, N, K, ldc, coff, relu);
  };

  // LSTM layer 0
  gemm(x, w_ih0, b_ih0, b_hh0, pre, 384, 64, 384, 0, 0);
  lstm_kernel<<<dim3(BATCH), dim3(768), 0, stream>>>(pre, w_hh0, bufA);
  // LSTM layer 1
  gemm(bufA, w_ih1, b_ih1, b_hh1, pre, 384, 96, 384, 0, 0);
  lstm_kernel<<<dim3(BATCH), dim3(768), 0, stream>>>(pre, w_hh1, bufB);
  // sparse attention
  gemm(bufB, qw, nullptr, nullptr, pre, 96, 96, QKV_LD, 0,   0);
  gemm(bufB, kw, nullptr, nullptr, pre, 96, 96, QKV_LD, 96,  0);
  gemm(bufB, vw, nullptr, nullptr, pre, 96, 96, QKV_LD, 192, 0);
  attn_kernel<<<dim3(8192), dim3(512), 0, stream>>>(pre, bufA, 1);
  gemm(bufA, ow, nullptr, nullptr, bufB, 96, 96, 96, 0, 0);
  // encoder layer 0 (full)
  gemm(bufB, enc_in_w, enc_in_b, nullptr, pre, 288, 96, QKV_LD, 0, 0);
  attn_kernel<<<dim3(8192), dim3(512), 0, stream>>>(pre, bufA, 0);
  gemm(bufA, enc_out_w, enc_out_b, nullptr, bufC, 96, 96, 96, 0, 0);
  resln_kernel<<<dim3(4096), dim3(256), 0, stream>>>(bufB, bufC, enc_ln1_w, enc_ln1_b, bufB);
  gemm(bufB, enc_l1_w, enc_l1_b, nullptr, pre, 192, 96, 192, 0, 1);
  gemm(pre, enc_l2_w, enc_l2_b, nullptr, bufC, 96, 192, 96, 0, 0);
  resln_kernel<<<dim3(4096), dim3(256), 0, stream>>>(bufB, bufC, enc_ln2_w, enc_ln2_b, bufB);
  // encoder layer 1 — only t = T-1 reaches the output head
  gemm(bufB, enc_in_w + 288*96, enc_in_b + 288, nullptr, pre, 288, 96, QKV_LD, 0, 0);
  attn_last_kernel<<<dim3(64), dim3(64), 0, stream>>>(pre, bufA);
  tail_kernel<<<dim3(BATCH), dim3(192), 0, stream>>>(
      bufB, bufA,
      enc_out_w + 96*96, enc_out_b + 96,
      enc_l1_w + 192*96, enc_l1_b + 192,
      enc_l2_w + 96*192, enc_l2_b + 96,
      enc_ln1_w + 96, enc_ln1_b + 96,
      enc_ln2_w + 96, enc_ln2_b + 96,
      fc_w, fc_b, outp);
}

// Round 4
// 2186.521 us; speedup vs baseline: 1.4389x; 1.0160x over previous
//
#include <hip/hip_runtime.h>
#include <cstdint>
#include <cmath>

#define T_SEQ 1024
#define BATCH 16
#define HID 96
#define G4 384
#define QKV_LD 288
#define HDIM 24
#define KKEEP 512
#define SCALE 0.20412414523193154f  // 1/sqrt(24)
#define L2E 1.4426950408889634f     // log2(e)

__device__ __forceinline__ float wred_sum(float v){
#pragma unroll
  for (int o=32;o;o>>=1) v += __shfl_xor(v,o,64);
  return v;
}
__device__ __forceinline__ float wred_max(float v){
#pragma unroll
  for (int o=32;o;o>>=1) v = fmaxf(v,__shfl_xor(v,o,64));
  return v;
}
__device__ __forceinline__ int wred_sumi(int v){
#pragma unroll
  for (int o=32;o;o>>=1) v += __shfl_xor(v,o,64);
  return v;
}
__device__ __forceinline__ unsigned fmono(float f){
  unsigned u = __float_as_uint(f);
  return (u & 0x80000000u) ? ~u : (u | 0x80000000u);
}

// ---------------- generic tiled GEMM: C[m, coff+n] = act(A[M,K] @ W[N,K]^T + b1 + b2)
__global__ __launch_bounds__(256)
void gemm_kernel(const float* __restrict__ A, const float* __restrict__ W,
                 const float* __restrict__ b1, const float* __restrict__ b2,
                 float* __restrict__ C, int M, int N, int K,
                 int ldc, int coff, int relu)
{
  __shared__ float As[16][68];
  __shared__ float Ws[16][68];
  const int tid = threadIdx.x;
  const int tx = tid & 15, ty = tid >> 4;
  const int m0 = blockIdx.y * 64, n0 = blockIdx.x * 64;
  const int lrow = tid >> 2, lcol = (tid & 3) * 4;
  float acc[4][4] = {};
  for (int k0 = 0; k0 < K; k0 += 16) {
    float4 a = {0,0,0,0}, w = {0,0,0,0};
    int gm = m0 + lrow;
    if (gm < M) a = *(const float4*)(A + (size_t)gm*K + k0 + lcol);
    int gn = n0 + lrow;
    if (gn < N) w = *(const float4*)(W + (size_t)gn*K + k0 + lcol);
    __syncthreads();
    As[lcol+0][lrow]=a.x; As[lcol+1][lrow]=a.y; As[lcol+2][lrow]=a.z; As[lcol+3][lrow]=a.w;
    Ws[lcol+0][lrow]=w.x; Ws[lcol+1][lrow]=w.y; Ws[lcol+2][lrow]=w.z; Ws[lcol+3][lrow]=w.w;
    __syncthreads();
#pragma unroll
    for (int kk=0;kk<16;++kk){
      const float4 av = *(const float4*)&As[kk][ty*4];
      const float4 wv = *(const float4*)&Ws[kk][tx*4];
      float a_[4]={av.x,av.y,av.z,av.w};
      float w_[4]={wv.x,wv.y,wv.z,wv.w};
#pragma unroll
      for (int i=0;i<4;++i)
#pragma unroll
        for (int j=0;j<4;++j) acc[i][j] += a_[i]*w_[j];
    }
  }
#pragma unroll
  for (int i=0;i<4;++i){
    int gm = m0 + ty*4 + i;
    if (gm >= M) continue;
#pragma unroll
    for (int j=0;j<4;++j){
      int gn = n0 + tx*4 + j;
      if (gn >= N) continue;
      float v = acc[i][j];
      if (b1) v += b1[gn];
      if (b2) v += b2[gn];
      if (relu) v = fmaxf(v, 0.f);
      C[(size_t)gm*ldc + coff + gn] = v;
    }
  }
}

// ---------------- sequential LSTM, 1 barrier per step, 2 gate-rows per thread.
// tid = j*8 + p*4 + q: column j (0..95), gate-pair p (0..1), K-quarter q (0..3).
// Thread computes rows {p*96+j, (p+2)*96+j} over its 24-wide K slice (one
// LDS h-read feeds 2 rows -> half the LDS insts). Butterfly xor(1),xor(2)
// finishes both dots; activations in-thread; xor(4) swaps the activated pair
// across p; c replicated per column (bitwise-identical in all 8 threads).
__global__ __launch_bounds__(768)
void lstm_kernel(const float* __restrict__ pre, const float* __restrict__ w_hh,
                 float* __restrict__ hout)
{
  const int b = blockIdx.x;
  const int tid = threadIdx.x;
  const int q = tid & 3, p = (tid >> 2) & 1, j = tid >> 3;
  const int rowA = p*96 + j;          // gate i (p=0) or f (p=1): sigmoid
  const int rowB = (p+2)*96 + j;      // gate g (p=0, tanh) or o (p=1, sigmoid)
  float wA[24], wB[24];
  {
    const float* wpA = w_hh + rowA*96 + q*24;
    const float* wpB = w_hh + rowB*96 + q*24;
#pragma unroll
    for (int k=0;k<24;k+=4){
      float4 ta = *(const float4*)(wpA + k);
      float4 tb = *(const float4*)(wpB + k);
      wA[k]=ta.x; wA[k+1]=ta.y; wA[k+2]=ta.z; wA[k+3]=ta.w;
      wB[k]=tb.x; wB[k+1]=tb.y; wB[k+2]=tb.z; wB[k+3]=tb.w;
    }
  }
  // gate B activation constants: act = A + B*rcp(1+exp2(C*x))
  // p=0 (tanh): A=1,B=-2,C=+2*log2e ; p=1 (sigmoid): A=0,B=1,C=-log2e
  const float Ab = p ? 0.f : 1.f;
  const float Bb = p ? 1.f : -2.f;
  const float Cb = p ? -L2E : 2.f*L2E;

  __shared__ float h_lds[96];
  float c = 0.f;
  if (tid < 96) h_lds[tid] = 0.f;
  __syncthreads();

  const float* prowA = pre + (size_t)b*T_SEQ*G4 + rowA;
  const float* prowB = pre + (size_t)b*T_SEQ*G4 + rowB;
  float* hrow = hout + (size_t)b*T_SEQ*HID;
  float pfA[4], pfB[4];
#pragma unroll
  for (int i=0;i<4;++i){ pfA[i] = prowA[(size_t)i*G4]; pfB[i] = prowB[(size_t)i*G4]; }

  for (int tb=0; tb<T_SEQ; tb+=4){
#pragma unroll
    for (int u=0; u<4; ++u){
      const int t = tb + u;
      const float pA = pfA[u], pB = pfB[u];
      int tn = t + 4; if (tn > T_SEQ-1) tn = T_SEQ-1;
      pfA[u] = prowA[(size_t)tn*G4];        // prefetch 4 steps ahead
      pfB[u] = prowB[(size_t)tn*G4];
      const float4* hb = (const float4*)(h_lds + q*24);  // 4 addrs/wave, bank-disjoint
      float a0=0.f,a1=0.f,a2=0.f,a3=0.f;
      float b0=0.f,b1v=0.f,b2v=0.f,b3=0.f;
#pragma unroll
      for (int k=0;k<6;++k){
        const float4 hv4 = hb[k];
        a0 += wA[k*4+0]*hv4.x; a1 += wA[k*4+1]*hv4.y;
        a2 += wA[k*4+2]*hv4.z; a3 += wA[k*4+3]*hv4.w;
        b0 += wB[k*4+0]*hv4.x; b1v += wB[k*4+1]*hv4.y;
        b2v += wB[k*4+2]*hv4.z; b3 += wB[k*4+3]*hv4.w;
      }
      float sA = (a0+a1)+(a2+a3);
      float sB = (b0+b1v)+(b2v+b3);
      sA += __shfl_xor(sA, 1, 64);  sB += __shfl_xor(sB, 1, 64);
      sA += __shfl_xor(sA, 2, 64);  sB += __shfl_xor(sB, 2, 64);
      sA += pA; sB += pB;
      // in-thread activations
      const float actA = __builtin_amdgcn_rcpf(1.f + __builtin_amdgcn_exp2f(-L2E*sA)); // sigmoid
      const float actB = fmaf(Bb, __builtin_amdgcn_rcpf(1.f + __builtin_amdgcn_exp2f(Cb*sB)), Ab);
      // swap activated pair across p (lane bit 2)
      const float othA = __shfl_xor(actA, 4, 64);
      const float othB = __shfl_xor(actB, 4, 64);
      const float iv = p ? othA : actA;
      const float fv = p ? actA : othA;
      const float gv = p ? othB : actB;
      const float ov = p ? actB : othB;
      c = fmaf(fv, c, iv*gv);
      const float th = fmaf(-2.f, __builtin_amdgcn_rcpf(1.f + __builtin_amdgcn_exp2f(c*(2.f*L2E))), 1.f);
      const float hv = ov*th;
      if ((tid & 7) == 0){
        h_lds[j] = hv;
        hrow[t*HID + j] = hv;
      }
      __syncthreads();
    }
  }
}

// ---------------- attention over full rows (sparse top-k optional)
// qkv layout: [B*T][288] (q|k|v). One wave per q-row, 8 rows/WG share staged K/V.
__global__ __launch_bounds__(512)
void attn_kernel(const float* __restrict__ qkv, float* __restrict__ out, int sparse)
{
  __shared__ float kl[24][260];
  const int tid = threadIdx.x;
  const int wave = tid >> 6, lane = tid & 63;
  const int bh = blockIdx.x >> 7;            // 128 blocks per (b,h)
  const int b = bh >> 2, h = bh & 3;
  const int tq = ((blockIdx.x & 127) << 3) + wave;
  const size_t base = (size_t)b * T_SEQ;
  const int hoff = h * HDIM;
  float q[24];
  {
    const float* qp = qkv + (base + tq)*QKV_LD + hoff;
#pragma unroll
    for (int d4=0; d4<6; ++d4){
      float4 t = *(const float4*)(qp + d4*4);
      q[d4*4]=t.x; q[d4*4+1]=t.y; q[d4*4+2]=t.z; q[d4*4+3]=t.w;
    }
  }
  float sc[16];
  // pass A: scores (lane owns s = c*256 + lane*4 + j)
  for (int c=0;c<4;++c){
    __syncthreads();
#pragma unroll
    for (int rep=0;rep<3;++rep){
      int p = rep*512 + tid;
      int sl = p/6, d4 = p - sl*6;
      const float4 kv = *(const float4*)(qkv + (base + (c<<8) + sl)*QKV_LD + 96 + hoff + d4*4);
      kl[d4*4+0][sl]=kv.x; kl[d4*4+1][sl]=kv.y; kl[d4*4+2][sl]=kv.z; kl[d4*4+3][sl]=kv.w;
    }
    __syncthreads();
    float a0=0.f,a1=0.f,a2=0.f,a3=0.f;
#pragma unroll
    for (int d=0; d<24; ++d){
      const float4 kd = *(const float4*)&kl[d][lane*4];
      a0 += q[d]*kd.x; a1 += q[d]*kd.y; a2 += q[d]*kd.z; a3 += q[d]*kd.w;
    }
    sc[c*4+0]=a0*SCALE; sc[c*4+1]=a1*SCALE; sc[c*4+2]=a2*SCALE; sc[c*4+3]=a3*SCALE;
  }
  // softmax (+ exact top-k mask)
  float m_loc = sc[0];
#pragma unroll
  for (int i=1;i<16;++i) m_loc = fmaxf(m_loc, sc[i]);
  const float m = wred_max(m_loc);
  float sum_loc = 0.f;
  if (sparse){
    unsigned u[16];
#pragma unroll
    for (int i=0;i<16;++i) u[i] = fmono(sc[i]);
    unsigned prefix = 0;
    for (int bit=31; bit>=0; --bit){
      unsigned test = prefix | (1u<<bit);
      int cnt = 0;
#pragma unroll
      for (int i=0;i<16;++i) cnt += (u[i] >= test) ? 1 : 0;
      cnt = wred_sumi(cnt);
      if (cnt >= KKEEP) prefix = test;
    }
#pragma unroll
    for (int i=0;i<16;++i){
      float e = (u[i] >= prefix) ? __expf(sc[i]-m) : 0.f;
      sc[i] = e; sum_loc += e;
    }
  } else {
#pragma unroll
    for (int i=0;i<16;++i){
      float e = __expf(sc[i]-m);
      sc[i] = e; sum_loc += e;
    }
  }
  const float inv = 1.f / wred_sum(sum_loc);
#pragma unroll
  for (int i=0;i<16;++i) sc[i] *= inv;
  // pass B: PV
  float acc[24] = {};
  for (int c=0;c<4;++c){
    __syncthreads();
#pragma unroll
    for (int rep=0;rep<3;++rep){
      int p = rep*512 + tid;
      int sl = p/6, d4 = p - sl*6;
      const float4 vv = *(const float4*)(qkv + (base + (c<<8) + sl)*QKV_LD + 192 + hoff + d4*4);
      kl[d4*4+0][sl]=vv.x; kl[d4*4+1][sl]=vv.y; kl[d4*4+2][sl]=vv.z; kl[d4*4+3][sl]=vv.w;
    }
    __syncthreads();
    const float w0=sc[c*4], w1=sc[c*4+1], w2=sc[c*4+2], w3=sc[c*4+3];
#pragma unroll
    for (int d=0; d<24; ++d){
      const float4 vd = *(const float4*)&kl[d][lane*4];
      acc[d] += w0*vd.x + w1*vd.y + w2*vd.z + w3*vd.w;
    }
  }
#pragma unroll
  for (int d=0; d<24; ++d) acc[d] = wred_sum(acc[d]);
  if (lane == 0){
    float* op = out + (base + tq)*HID + hoff;
#pragma unroll
    for (int d4=0; d4<6; ++d4){
      float4 t = {acc[d4*4], acc[d4*4+1], acc[d4*4+2], acc[d4*4+3]};
      *(float4*)(op + d4*4) = t;
    }
  }
}

// ---------------- dense attention for t = T-1 only (encoder 2): 64 rows, 1 wave each
__global__ __launch_bounds__(64)
void attn_last_kernel(const float* __restrict__ qkv, float* __restrict__ out)
{
  const int bh = blockIdx.x, b = bh>>2, h = bh&3;
  const int lane = threadIdx.x;
  const size_t base = (size_t)b*T_SEQ;
  const int hoff = h*HDIM;
  float q[24];
  {
    const float* qp = qkv + (base + T_SEQ-1)*QKV_LD + hoff;
#pragma unroll
    for (int d4=0; d4<6; ++d4){
      float4 t = *(const float4*)(qp + d4*4);
      q[d4*4]=t.x; q[d4*4+1]=t.y; q[d4*4+2]=t.z; q[d4*4+3]=t.w;
    }
  }
  float sc[16];
#pragma unroll 4
  for (int i=0;i<16;++i){
    const float* kp = qkv + (base + i*64 + lane)*QKV_LD + 96 + hoff;
    float a = 0.f;
#pragma unroll
    for (int d4=0; d4<6; ++d4){
      float4 kv = *(const float4*)(kp + d4*4);
      a += q[d4*4]*kv.x + q[d4*4+1]*kv.y + q[d4*4+2]*kv.z + q[d4*4+3]*kv.w;
    }
    sc[i] = a*SCALE;
  }
  float m_loc = sc[0];
#pragma unroll
  for (int i=1;i<16;++i) m_loc = fmaxf(m_loc, sc[i]);
  const float m = wred_max(m_loc);
  float sum_loc = 0.f;
#pragma unroll
  for (int i=0;i<16;++i){ sc[i] = __expf(sc[i]-m); sum_loc += sc[i]; }
  const float inv = 1.f / wred_sum(sum_loc);
  float acc[24] = {};
#pragma unroll 4
  for (int i=0;i<16;++i){
    const float* vp = qkv + (base + i*64 + lane)*QKV_LD + 192 + hoff;
    const float wgt = sc[i]*inv;
#pragma unroll
    for (int d4=0; d4<6; ++d4){
      float4 vv = *(const float4*)(vp + d4*4);
      acc[d4*4]   += wgt*vv.x; acc[d4*4+1] += wgt*vv.y;
      acc[d4*4+2] += wgt*vv.z; acc[d4*4+3] += wgt*vv.w;
    }
  }
#pragma unroll
  for (int d=0; d<24; ++d) acc[d] = wred_sum(acc[d]);
  if (lane == 0){
    float* op = out + (base + T_SEQ-1)*HID + hoff;
#pragma unroll
    for (int d4=0; d4<6; ++d4){
      float4 t = {acc[d4*4], acc[d4*4+1], acc[d4*4+2], acc[d4*4+3]};
      *(float4*)(op + d4*4) = t;
    }
  }
}

// ---------------- out = LayerNorm(x + y) * w + b ; one wave per 96-wide row
__global__ __launch_bounds__(256)
void resln_kernel(const float* __restrict__ x, const float* __restrict__ y,
                  const float* __restrict__ w, const float* __restrict__ bb,
                  float* __restrict__ out)
{
  const int row = blockIdx.x*4 + (threadIdx.x>>6);
  const int lane = threadIdx.x & 63;
  const float* xr = x + (size_t)row*HID;
  const float* yr = y + (size_t)row*HID;
  float v0 = xr[lane] + yr[lane];
  float v1 = (lane < 32) ? (xr[64+lane] + yr[64+lane]) : 0.f;
  float mu = wred_sum(v0+v1) * (1.f/96.f);
  float d0 = v0-mu, d1 = (lane<32) ? (v1-mu) : 0.f;
  float var = wred_sum(d0*d0 + d1*d1) * (1.f/96.f);
  float rs = rsqrtf(var + 1e-5f);
  float* orow = out + (size_t)row*HID;
  orow[lane] = d0*rs*w[lane] + bb[lane];
  if (lane < 32) orow[64+lane] = d1*rs*w[64+lane] + bb[64+lane];
}

// ---------------- encoder-2 tail at t=T-1 only: proj+LN1+FF+LN2+fc
__device__ __forceinline__ float block_sum_192(float v, float* red){
  v = wred_sum(v);
  const int tid = threadIdx.x;
  if ((tid & 63) == 0) red[tid>>6] = v;
  __syncthreads();
  float r = red[0]+red[1]+red[2];
  __syncthreads();
  return r;
}

__global__ __launch_bounds__(192)
void tail_kernel(const float* __restrict__ xin, const float* __restrict__ mha,
                 const float* __restrict__ out_w, const float* __restrict__ out_b,
                 const float* __restrict__ l1_w, const float* __restrict__ l1_b,
                 const float* __restrict__ l2_w, const float* __restrict__ l2_b,
                 const float* __restrict__ ln1w, const float* __restrict__ ln1b,
                 const float* __restrict__ ln2w, const float* __restrict__ ln2b,
                 const float* __restrict__ fcw, const float* __restrict__ fcb,
                 float* __restrict__ outp)
{
  const int b = blockIdx.x, tid = threadIdx.x;
  __shared__ float y[96], f1[192], mrow[96], red[3];
  const size_t row = ((size_t)b*T_SEQ + T_SEQ-1)*HID;
  if (tid < 96) mrow[tid] = mha[row + tid];
  __syncthreads();
  float r = 0.f;
  if (tid < 96){
    float p = out_b[tid];
    const float* wr = out_w + tid*96;
#pragma unroll 4
    for (int d=0; d<96; ++d) p += mrow[d]*wr[d];
    r = xin[row + tid] + p;
  }
  float mu = block_sum_192(tid<96 ? r : 0.f, red) * (1.f/96.f);
  float dv = tid<96 ? r-mu : 0.f;
  float var = block_sum_192(dv*dv, red) * (1.f/96.f);
  float rs = rsqrtf(var + 1e-5f);
  if (tid < 96) y[tid] = dv*rs*ln1w[tid] + ln1b[tid];
  __syncthreads();
  {
    float a = l1_b[tid];
    const float* wr = l1_w + tid*96;
#pragma unroll 4
    for (int d=0; d<96; ++d) a += y[d]*wr[d];
    f1[tid] = fmaxf(a, 0.f);
  }
  __syncthreads();
  float r2 = 0.f;
  if (tid < 96){
    float a = l2_b[tid];
    const float* wr = l2_w + tid*192;
#pragma unroll 4
    for (int d=0; d<192; ++d) a += f1[d]*wr[d];
    r2 = y[tid] + a;
  }
  float mu2 = block_sum_192(tid<96 ? r2 : 0.f, red) * (1.f/96.f);
  float dv2 = tid<96 ? r2-mu2 : 0.f;
  float var2 = block_sum_192(dv2*dv2, red) * (1.f/96.f);
  float rs2 = rsqrtf(var2 + 1e-5f);
  float z = tid<96 ? (dv2*rs2*ln2w[tid] + ln2b[tid]) : 0.f;
  float tot = block_sum_192(tid<96 ? z*fcw[tid] : 0.f, red);
  if (tid == 0) outp[b] = tot + fcb[0];
}

extern "C" void kernel_launch(void* const* d_in, const int* in_sizes, int n_in,
                              void* d_out, int out_size, void* d_ws, size_t ws_size,
                              hipStream_t stream)
{
  const float* x     = (const float*)d_in[0];
  const float* w_ih0 = (const float*)d_in[1];
  const float* w_hh0 = (const float*)d_in[2];
  const float* b_ih0 = (const float*)d_in[3];
  const float* b_hh0 = (const float*)d_in[4];
  const float* w_ih1 = (const float*)d_in[5];
  const float* w_hh1 = (const float*)d_in[6];
  const float* b_ih1 = (const float*)d_in[7];
  const float* b_hh1 = (const float*)d_in[8];
  const float* qw = (const float*)d_in[9];
  const float* kw = (const float*)d_in[10];
  const float* vw = (const float*)d_in[11];
  const float* ow = (const float*)d_in[12];
  const float* enc_in_w  = (const float*)d_in[13];
  const float* enc_in_b  = (const float*)d_in[14];
  const float* enc_out_w = (const float*)d_in[15];
  const float* enc_out_b = (const float*)d_in[16];
  const float* enc_l1_w  = (const float*)d_in[17];
  const float* enc_l1_b  = (const float*)d_in[18];
  const float* enc_l2_w  = (const float*)d_in[19];
  const float* enc_l2_b  = (const float*)d_in[20];
  const float* enc_ln1_w = (const float*)d_in[21];
  const float* enc_ln1_b = (const float*)d_in[22];
  const float* enc_ln2_w = (const float*)d_in[23];
  const float* enc_ln2_b = (const float*)d_in[24];
  const float* fc_w = (const float*)d_in[25];
  const float* fc_b = (const float*)d_in[26];
  float* outp = (float*)d_out;

  float* ws = (float*)d_ws;
  const size_t MT = (size_t)BATCH*T_SEQ;   // 16384
  float* pre  = ws;                        // 16384*384 (also qkv[288] / ff1[192])
  float* bufA = pre  + MT*G4;
  float* bufB = bufA + MT*HID;
  float* bufC = bufB + MT*HID;

  const int M = (int)MT;
  auto gemm = [&](const float* A, const float* W, const float* bb1, const float* bb2,
                  float* C, int N, int K, int ldc, int coff, int relu){
    dim3 grid((N+63)/64, M/64);
    gemm_kernel<<<grid, dim3(256), 0, stream>>>(A, W, bb1, bb2, C, M, N, K, ldc, coff, relu);
  };

  // LSTM layer 0
  gemm(x, w_ih0, b_ih0, b_hh0, pre, 384, 64, 384, 0, 0);
  lstm_kernel<<<dim3(BATCH), dim3(768), 0, stream>>>(pre, w_hh0, bufA);
  // LSTM layer 1
  gemm(bufA, w_ih1, b_ih1, b_hh1, pre, 384, 96, 384, 0, 0);
  lstm_kernel<<<dim3(BATCH), dim3(768), 0, stream>>>(pre, w_hh1, bufB);
  // sparse attention
  gemm(bufB, qw, nullptr, nullptr, pre, 96, 96, QKV_LD, 0,   0);
  gemm(bufB, kw, nullptr, nullptr, pre, 96, 96, QKV_LD, 96,  0);
  gemm(bufB, vw, nullptr, nullptr, pre, 96, 96, QKV_LD, 192, 0);
  attn_kernel<<<dim3(8192), dim3(512), 0, stream>>>(pre, bufA, 1);
  gemm(bufA, ow, nullptr, nullptr, bufB, 96, 96, 96, 0, 0);
  // encoder layer 0 (full)
  gemm(bufB, enc_in_w, enc_in_b, nullptr, pre, 288, 96, QKV_LD, 0, 0);
  attn_kernel<<<dim3(8192), dim3(512), 0, stream>>>(pre, bufA, 0);
  gemm(bufA, enc_out_w, enc_out_b, nullptr, bufC, 96, 96, 96, 0, 0);
  resln_kernel<<<dim3(4096), dim3(256), 0, stream>>>(bufB, bufC, enc_ln1_w, enc_ln1_b, bufB);
  gemm(bufB, enc_l1_w, enc_l1_b, nullptr, pre, 192, 96, 192, 0, 1);
  gemm(pre, enc_l2_w, enc_l2_b, nullptr, bufC, 96, 192, 96, 0, 0);
  resln_kernel<<<dim3(4096), dim3(256), 0, stream>>>(bufB, bufC, enc_ln2_w, enc_ln2_b, bufB);
  // encoder layer 1 — only t = T-1 reaches the output head
  gemm(bufB, enc_in_w + 288*96, enc_in_b + 288, nullptr, pre, 288, 96, QKV_LD, 0, 0);
  attn_last_kernel<<<dim3(64), dim3(64), 0, stream>>>(pre, bufA);
  tail_kernel<<<dim3(BATCH), dim3(192), 0, stream>>>(
      bufB, bufA,
      enc_out_w + 96*96, enc_out_b + 96,
      enc_l1_w + 192*96, enc_l1_b + 192,
      enc_l2_w + 96*192, enc_l2_b + 96,
      enc_ln1_w + 96, enc_ln1_b + 96,
      enc_ln2_w + 96, enc_ln2_b + 96,
      fc_w, fc_b, outp);
}